// Round 7
// baseline (86.338 us; speedup 1.0000x reference)
//
#include <hip/hip_runtime.h>
#include <hip/hip_bf16.h>

// LSTM cell fused: C = [x|h] @ [Wx|Wh]^T (gate-per-16col-fragment N layout).
// GEMM M=4096, N=4096, K=2048. 256x256 tile, BK=64, 8 waves (2Mx4N).
// R7: free-running tile body — full 2-tile LDS double-buffer means NO
// intra-tile hazards, so exactly ONE s_barrier + ONE vmcnt(0) per K-tile.
// All 8 stages issued at tile start (land during tile -> drain free);
// all 24 ds_read_b128 issued up front; 64 MFMA; compiler lgkmcnt deps.
// XOR swizzle byte ^= (row&7)<<4 (0 bank conflicts), XCD swizzle.

constexpr int Mdim = 4096;
constexpr int Ndim = 4096;
constexpr int Kdim = 2048;
constexpr int Hdim = 1024;
constexpr int BM = 256;
constexpr int BN = 256;
constexpr int BK = 64;
constexpr int NT = Kdim / BK;   // 32 K-tiles

using short8 = __attribute__((ext_vector_type(8))) short;
using f32x4  = __attribute__((ext_vector_type(4))) float;

__device__ __forceinline__ float sigmoid_(float x) {
    return 1.f / (1.f + __expf(-x));
}
__device__ __forceinline__ float tanh_(float x) {
    float e = __expf(2.f * x);
    return (e - 1.f) / (e + 1.f);
}

// ---- build A = [x | h] as bf16 [4096][2048] ----
__global__ void build_A(const float* __restrict__ x, const float* __restrict__ h,
                        __hip_bfloat16* __restrict__ A) {
    int idx = blockIdx.x * 256 + threadIdx.x;
    int row = idx >> 8;
    int c8  = (idx & 255) * 8;
    const float* src = (c8 < 1024) ? (x + (size_t)row * 1024 + c8)
                                   : (h + (size_t)row * 1024 + (c8 - 1024));
    float4 f0 = ((const float4*)src)[0];
    float4 f1 = ((const float4*)src)[1];
    union { short8 v; __hip_bfloat16 e[8]; } u;
    u.e[0] = __float2bfloat16(f0.x); u.e[1] = __float2bfloat16(f0.y);
    u.e[2] = __float2bfloat16(f0.z); u.e[3] = __float2bfloat16(f0.w);
    u.e[4] = __float2bfloat16(f1.x); u.e[5] = __float2bfloat16(f1.y);
    u.e[6] = __float2bfloat16(f1.z); u.e[7] = __float2bfloat16(f1.w);
    *(short8*)(A + (size_t)row * Kdim + c8) = u.v;
}

// ---- build B: row n -> gate g=(n>>4)&3, unit j=((n>>6)<<4)|(n&15) ----
__global__ void build_B(const float* __restrict__ Wxi, const float* __restrict__ Whi,
                        const float* __restrict__ Wxf, const float* __restrict__ Whf,
                        const float* __restrict__ Wxg, const float* __restrict__ Whg,
                        const float* __restrict__ Wxo, const float* __restrict__ Who,
                        __hip_bfloat16* __restrict__ B) {
    int idx = blockIdx.x * 256 + threadIdx.x;
    int n  = idx >> 8;
    int c8 = (idx & 255) * 8;
    int g = (n >> 4) & 3;
    int j = ((n >> 6) << 4) | (n & 15);
    const float* Wx = (g == 0) ? Wxi : (g == 1) ? Wxf : (g == 2) ? Wxg : Wxo;
    const float* Wh = (g == 0) ? Whi : (g == 1) ? Whf : (g == 2) ? Whg : Who;
    const float* src = (c8 < 1024) ? (Wx + (size_t)j * 1024 + c8)
                                   : (Wh + (size_t)j * 1024 + (c8 - 1024));
    float4 f0 = ((const float4*)src)[0];
    float4 f1 = ((const float4*)src)[1];
    union { short8 v; __hip_bfloat16 e[8]; } u;
    u.e[0] = __float2bfloat16(f0.x); u.e[1] = __float2bfloat16(f0.y);
    u.e[2] = __float2bfloat16(f0.z); u.e[3] = __float2bfloat16(f0.w);
    u.e[4] = __float2bfloat16(f1.x); u.e[5] = __float2bfloat16(f1.y);
    u.e[6] = __float2bfloat16(f1.z); u.e[7] = __float2bfloat16(f1.w);
    *(short8*)(B + (size_t)n * Kdim + c8) = u.v;
}

#define RD(p) (*(const short8*)(p))

// ---- fused GEMM + LSTM epilogue, 1-barrier-per-tile free-run ----
__launch_bounds__(512, 1)
__global__ void lstm_gemm(const __hip_bfloat16* __restrict__ A,
                          const __hip_bfloat16* __restrict__ B,
                          const float* __restrict__ c_prev,
                          const float* __restrict__ b_i, const float* __restrict__ b_f,
                          const float* __restrict__ b_g, const float* __restrict__ b_o,
                          float* __restrict__ out_h, float* __restrict__ out_c) {
    // [dbuf][A=0/B=1][half][128 rows x 64 cols bf16] = 8 regions x 16 KB = 128 KiB
    __shared__ __hip_bfloat16 lds[2][2][2][128 * 64];

    const int tid  = threadIdx.x;
    const int lane = tid & 63;
    const int w    = tid >> 6;          // 0..7
    const int wr   = w >> 2;            // 0..1 (M half)
    const int wc   = w & 3;             // 0..3 (N quarter)
    const int l15  = lane & 15, lhi = lane >> 4;

    // XCD-aware swizzle (nwg = 256, divisible by 8)
    int bid = blockIdx.x;
    int swz = (bid & 7) * 32 + (bid >> 3);
    const int bm = (swz >> 4) * BM;
    const int bn = (swz & 15) * BN;

    // Staging: thread writes LDS bytes [byteoff + tid*16); LDS row = byteoff/8192*64
    // + tid>>3, chunk = tid&7. Source col pre-permuted: (tid&7) ^ ((tid>>3)&7).
    const int srow_  = tid >> 3;
    const int schunk = ((tid & 7) ^ ((tid >> 3) & 7)) * 8;

    // ds_read swizzle: byte-in-row = (kk*64 + lhi*16) ^ ((row&7)<<4), row&7 == l15&7
    const int swz4 = (l15 & 7) << 4;
    const int kof0 = (lhi * 16) ^ swz4;
    const int kof1 = (64 + lhi * 16) ^ swz4;

#define STG1(dstbase, byteoff, srcptr, grow, kcol)                              \
    __builtin_amdgcn_global_load_lds(                                           \
        (const __attribute__((address_space(1))) unsigned*)(                    \
            (srcptr) + (size_t)((grow) + srow_) * Kdim + (kcol) + schunk),      \
        (__attribute__((address_space(3))) unsigned*)(                          \
            (char*)(dstbase) + (byteoff) + tid * 16), 16, 0, 0)

    // stage all 4 regions (8 chunks) of one K-tile into dbuf s
#define STAGE_TILE(s, kc)                                                       \
    do {                                                                        \
        STG1(&lds[s][1][0][0], 0,    B, bn + 0,   kc);                          \
        STG1(&lds[s][1][0][0], 8192, B, bn + 64,  kc);                          \
        STG1(&lds[s][1][1][0], 0,    B, bn + 128, kc);                          \
        STG1(&lds[s][1][1][0], 8192, B, bn + 192, kc);                          \
        STG1(&lds[s][0][0][0], 0,    A, bm + 0,   kc);                          \
        STG1(&lds[s][0][0][0], 8192, A, bm + 64,  kc);                          \
        STG1(&lds[s][0][1][0], 0,    A, bm + 128, kc);                          \
        STG1(&lds[s][0][1][0], 8192, A, bm + 192, kc);                          \
    } while (0)

    f32x4 acc[8][4];
#pragma unroll
    for (int a = 0; a < 8; ++a)
#pragma unroll
        for (int b = 0; b < 4; ++b)
            acc[a][b] = (f32x4){0.f, 0.f, 0.f, 0.f};

    // ---- prologue: stage tile 0, drain ----
    STAGE_TILE(0, 0);
    __builtin_amdgcn_sched_barrier(0);
    asm volatile("s_waitcnt vmcnt(0)" ::: "memory");
    __builtin_amdgcn_s_barrier();

    for (int t = 0; t < NT; ++t) {
        const int d = t & 1;

        // issue next tile's 8 staging loads first (land during this tile's math)
        if (t + 1 < NT) STAGE_TILE(d ^ 1, (t + 1) * BK);

        const char* Ab = (const char*)&lds[d][0][wr][0] + l15 * 128;
        const char* Bb = (const char*)&lds[d][1][wc >> 1][0] + ((wc & 1) * 64 + l15) * 128;

        // all 24 ds_read_b128 up front; compiler handles lgkmcnt deps
        short8 af[8][2], bf[4][2];
#pragma unroll
        for (int a = 0; a < 8; ++a) {
            af[a][0] = RD(Ab + a * 2048 + kof0);
            af[a][1] = RD(Ab + a * 2048 + kof1);
        }
#pragma unroll
        for (int b = 0; b < 4; ++b) {
            bf[b][0] = RD(Bb + b * 2048 + kof0);
            bf[b][1] = RD(Bb + b * 2048 + kof1);
        }

        __builtin_amdgcn_s_setprio(1);
#pragma unroll
        for (int a = 0; a < 8; ++a)
#pragma unroll
            for (int b = 0; b < 4; ++b)
#pragma unroll
                for (int kk = 0; kk < 2; ++kk)
                    acc[a][b] = __builtin_amdgcn_mfma_f32_16x16x32_bf16(
                        af[a][kk], bf[b][kk], acc[a][b], 0, 0, 0);
        __builtin_amdgcn_s_setprio(0);

        // single tile-boundary sync: pin everything above, drain loads+reads,
        // barrier. (lgkmcnt(0) guarantees no queued ds_read is serviced after
        // another wave's post-barrier LDS write; vmcnt(0) = t+1 regions landed,
        // issued a full tile ago -> free.)
        if (t + 1 < NT) {
            __builtin_amdgcn_sched_barrier(0);
            asm volatile("s_waitcnt vmcnt(0) lgkmcnt(0)" ::: "memory");
            __builtin_amdgcn_s_barrier();
        }
    }
#undef STG1
#undef STAGE_TILE

    // ---- fused LSTM epilogue (shuffle-free) ----
    const int j0 = ((bn + wc * 64) >> 6) * 16 + l15;
    const float bi  = b_i[j0];
    const float bf_ = b_f[j0];
    const float bg  = b_g[j0];
    const float bo  = b_o[j0];

#pragma unroll
    for (int a = 0; a < 8; ++a) {
        int mbase = bm + wr * 128 + a * 16 + lhi * 4;
#pragma unroll
        for (int r = 0; r < 4; ++r) {
            int m = mbase + r;
            float vi = acc[a][0][r] + bi;
            float vf = acc[a][1][r] + bf_;
            float vg = acc[a][2][r] + bg;
            float vo = acc[a][3][r] + bo;
            float it = sigmoid_(vi);
            float ft = sigmoid_(vf);
            float gt = tanh_(vg);
            float ot = sigmoid_(vo);
            float cp = c_prev[(size_t)m * Hdim + j0];
            float ct = ft * cp + it * gt;
            float ht = ot * tanh_(ct);
            out_h[(size_t)m * Hdim + j0] = ht;
            out_c[(size_t)m * Hdim + j0] = ct;
        }
    }
}

extern "C" void kernel_launch(void* const* d_in, const int* in_sizes, int n_in,
                              void* d_out, int out_size, void* d_ws, size_t ws_size,
                              hipStream_t stream) {
    const float* x_t    = (const float*)d_in[0];
    const float* h_prev = (const float*)d_in[1];
    const float* c_prev = (const float*)d_in[2];
    const float* W_xi   = (const float*)d_in[3];
    const float* W_hi   = (const float*)d_in[4];
    const float* b_i    = (const float*)d_in[5];
    const float* W_xf   = (const float*)d_in[6];
    const float* W_hf   = (const float*)d_in[7];
    const float* b_f    = (const float*)d_in[8];
    const float* W_xg   = (const float*)d_in[9];
    const float* W_hg   = (const float*)d_in[10];
    const float* b_g    = (const float*)d_in[11];
    const float* W_xo   = (const float*)d_in[12];
    const float* W_ho   = (const float*)d_in[13];
    const float* b_o    = (const float*)d_in[14];

    float* out_h = (float*)d_out;
    float* out_c = out_h + (size_t)Mdim * Hdim;

    __hip_bfloat16* Abf = (__hip_bfloat16*)d_ws;
    __hip_bfloat16* Bbf = Abf + (size_t)Mdim * Kdim;

    build_A<<<4096, 256, 0, stream>>>(x_t, h_prev, Abf);
    build_B<<<4096, 256, 0, stream>>>(W_xi, W_hi, W_xf, W_hf, W_xg, W_hg, W_xo, W_ho, Bbf);

    lstm_gemm<<<dim3((Mdim / BM) * (Ndim / BN)), 512, 0, stream>>>(
        Abf, Bbf, c_prev, b_i, b_f, b_g, b_o, out_h, out_c);
}